// Round 8
// baseline (262.084 us; speedup 1.0000x reference)
//
#include <hip/hip_runtime.h>
#include <math.h>

// Problem constants (B=8, F=32 -> 256 frames of 224x224x3 f32)
#define NFRAMES 256
#define NH 224
#define NW 224
#define NPIX (NH * NW)            // 50176
#define NOISE_LEN 766             // 3*L - 2
#define WIN_LEN 511               // 2*L - 1
#define TILE_W 32                 // tile width  (cols)
#define TILE_H 8                  // tile height (rows)
#define TILES_X (NW / TILE_W)     // 7
#define TILES_Y (NH / TILE_H)     // 28
#define BLOCKS_PER_FRAME (TILES_X * TILES_Y)  // 196

// ---------------------------------------------------------------------------
// Kernel 1 (unchanged): one block per frame (256 blocks -> one per CU).
// ---------------------------------------------------------------------------
__global__ __launch_bounds__(256) void build_mats_v2(
    const float* __restrict__ noise,   // (4, 766)
    const float* __restrict__ basis,   // (4, 3, 3)
    float* __restrict__ Mout) {        // (256, 9)
  const int b = blockIdx.x;      // frame index
  const int t = threadIdx.x;
  const int j = t >> 6;          // noise row (wave id)
  const int lane = t & 63;

  __shared__ double wsh[WIN_LEN];
  __shared__ double vsh[4];

  // weights w[k] = 1.1^(255 - |k-255|), k = 0..510
  for (int k = t; k < WIN_LEN; k += 256) {
    int e = 255 - abs(k - 255);
    wsh[k] = pow(1.1, (double)e);
  }
  __syncthreads();

  // sum(w) closed form: sum_{e=0}^{254} 1.1^e + sum_{e=0}^{255} 1.1^e
  const double S = (pow(1.1, 255.0) - 1.0) * 10.0 + (pow(1.1, 256.0) - 1.0) * 10.0;

  // conv (valid) at position b for row j: sum_{k=0}^{510} n[j][b+k] * w[k]
  const float* row = noise + j * NOISE_LEN + b;
  const int k0 = lane * 8;
  double acc = 0.0;
  #pragma unroll
  for (int i = 0; i < 8; ++i) {
    const int k = k0 + i;
    if (k < WIN_LEN) acc = fma((double)row[k], wsh[k], acc);
  }
  #pragma unroll
  for (int off = 32; off > 0; off >>= 1) acc += __shfl_down(acc, off, 64);
  if (lane == 0) {
    const double v = acc / S;
    vsh[j] = v > 0.0 ? v : 0.0;   // relu
  }
  __syncthreads();

  if (t == 0) {
    const double wv0 = vsh[0], wv1 = vsh[1], wv2 = vsh[2], wv3 = vsh[3];
    const double swv = wv0 + wv1 + wv2 + wv3;
    double warp[9];
    #pragma unroll
    for (int e = 0; e < 9; ++e) {
      warp[e] = wv0 * (double)basis[0 * 9 + e] + wv1 * (double)basis[1 * 9 + e] +
                wv2 * (double)basis[2 * 9 + e] + wv3 * (double)basis[3 * 9 + e];
    }
    warp[0] += 4.0 - swv;
    warp[4] += 4.0 - swv;
    warp[8] += 4.0 - swv;

    // M = [S(h-1,w-1) @ T(.5,.5)] @ warp @ [T(-.5,-.5) @ S(1/(h-1),1/(w-1))]
    const double W1 = (double)(NW - 1);
    const double H1 = (double)(NH - 1);
    double T[9];
    #pragma unroll
    for (int c = 0; c < 3; ++c) {
      T[0 * 3 + c] = W1 * warp[0 * 3 + c] + 0.5 * W1 * warp[2 * 3 + c];
      T[1 * 3 + c] = H1 * warp[1 * 3 + c] + 0.5 * H1 * warp[2 * 3 + c];
      T[2 * 3 + c] = warp[2 * 3 + c];
    }
    float* Mo = Mout + b * 9;
    #pragma unroll
    for (int r = 0; r < 3; ++r) {
      Mo[r * 3 + 0] = (float)(T[r * 3 + 0] / W1);
      Mo[r * 3 + 1] = (float)(T[r * 3 + 1] / H1);
      Mo[r * 3 + 2] = (float)(-0.5 * T[r * 3 + 0] - 0.5 * T[r * 3 + 1] + T[r * 3 + 2]);
    }
  }
}

// ---------------------------------------------------------------------------
// Kernel 2 (v10): 32x8-tile blocks, 1 px/thread.
// Post-r7: the 2x2-px/thread restructure (v9) failed the harness's
// post-timing same-work tripwire for reasons not provable by inspection --
// multi-px structure RETIRED. This restores the r6 structure exactly
// (1 px/thread, 256-px tile, 50176 blocks, identical sample code path)
// with the only remaining low-risk probe of the confirmed pattern lever:
// tile shape 16x16 -> 32x8.
//  Mechanism: 32-wide tiles make the source footprint row-contiguous
//  (9 rows x 33 cols; ~7 lines/row run) vs 16x16's 17x17 patch:
//  ~63 vs ~71 unique lines per 256 px, and a wave's gather instruction
//  spans ~2 source rows (was ~5) -> fewer lines/inst, DRAM-friendlier.
//  Kept: VALU-lean validity/clamp (r5), packed dwordx3 loads, NT stores.
//  Retired: XCD swizzle (r3, -12us), px-pair strip (r4), 2x2/thread (r7).
// Validity matches reference: un-clipped corner tests, clip-then-truncate
// indices, zero fill outside.
// ---------------------------------------------------------------------------
__global__ __launch_bounds__(256) void warp_bilinear_kernel(
    const float* __restrict__ x,     // (256, 224, 224, 3)
    const float* __restrict__ M,     // (256, 9)
    float* __restrict__ out) {       // (256, 224, 224, 3)
  const int bid = blockIdx.x;
  const int l = bid / BLOCKS_PER_FRAME;            // frame (block-uniform)
  const int tile = bid - l * BLOCKS_PER_FRAME;
  const int ty = tile / TILES_X;                   // 0..27
  const int tx = tile - ty * TILES_X;              // 0..6
  const int r = ty * TILE_H + (threadIdx.x >> 5);  // 8 rows per tile
  const int c = tx * TILE_W + (threadIdx.x & 31);  // 32 cols per tile
  const int p = r * NW + c;

  const float* Mp = M + l * 9;   // uniform -> scalar loads
  const float m00 = Mp[0], m01 = Mp[1], m02 = Mp[2];
  const float m10 = Mp[3], m11 = Mp[4], m12 = Mp[5];
  const float m20 = Mp[6], m21 = Mp[7], m22 = Mp[8];

  const float cf = (float)c, rf = (float)r;

  const float fx = fmaf(m00, cf, fmaf(m01, rf, m02));
  const float fy = fmaf(m10, cf, fmaf(m11, rf, m12));
  const float fz = fmaf(m20, cf, fmaf(m21, rf, m22));
  const float inv = __builtin_amdgcn_rcpf(fz);   // ~2^-22 rel err, in budget
  const float xs = fx * inv;
  const float ys = fy * inv;

  const float x0f = floorf(xs), y0f = floorf(ys);
  const float wx = xs - x0f, wy = ys - y0f;

  // Pre-clamp keeps cvt exact and in-range; [-2,225] preserves validity of
  // both corner tests (x0 in [0,223]; x1 valid iff x0 in [-1,222]).
  const float x0c = fminf(fmaxf(x0f, -2.0f), 225.0f);
  const float y0c = fminf(fmaxf(y0f, -2.0f), 225.0f);
  const int ix0 = (int)x0c, iy0 = (int)y0c;      // exact
  const int ix1 = ix0 + 1,  iy1 = iy0 + 1;

  const bool vx0 = (unsigned)ix0 <= (unsigned)(NW - 1);  // 0<=ix0<=223
  const bool vx1 = (unsigned)ix1 <= (unsigned)(NW - 1);
  const bool vy0 = (unsigned)iy0 <= (unsigned)(NH - 1);
  const bool vy1 = (unsigned)iy1 <= (unsigned)(NH - 1);

  const int xi0 = min(max(ix0, 0), NW - 1);      // v_med3_i32
  const int xi1 = min(max(ix1, 0), NW - 1);
  const int yi0 = min(max(iy0, 0), NH - 1);
  const int yi1 = min(max(iy1, 0), NH - 1);

  const float* img = x + (size_t)l * (NPIX * 3);
  const float* p00 = img + (yi0 * NW + xi0) * 3;
  const float* p01 = img + (yi0 * NW + xi1) * 3;
  const float* p10 = img + (yi1 * NW + xi0) * 3;
  const float* p11 = img + (yi1 * NW + xi1) * 3;

  // Packed 12-B corner fetches -> global_load_dwordx3 each.
  float q00[3], q01[3], q10[3], q11[3];
  __builtin_memcpy(q00, p00, 12);
  __builtin_memcpy(q01, p01, 12);
  __builtin_memcpy(q10, p10, 12);
  __builtin_memcpy(q11, p11, 12);

  // Axis weights with validity folded in (cndmask), then 4 corner muls.
  const float wxb = vx0 ? (1.0f - wx) : 0.0f;
  const float wxa = vx1 ? wx          : 0.0f;
  const float wyb = vy0 ? (1.0f - wy) : 0.0f;
  const float wya = vy1 ? wy          : 0.0f;
  const float w00 = wyb * wxb;
  const float w01 = wyb * wxa;
  const float w10 = wya * wxb;
  const float w11 = wya * wxa;

  const float o0 = w00 * q00[0] + w01 * q01[0] + w10 * q10[0] + w11 * q11[0];
  const float o1 = w00 * q00[1] + w01 * q01[1] + w10 * q10[1] + w11 * q11[1];
  const float o2 = w00 * q00[2] + w01 * q01[2] + w10 * q10[2] + w11 * q11[2];

  // Nontemporal: out is never re-read; keep L2/L3 for the gather set.
  float* op = out + ((size_t)l * NPIX + p) * 3;
  __builtin_nontemporal_store(o0, op + 0);
  __builtin_nontemporal_store(o1, op + 1);
  __builtin_nontemporal_store(o2, op + 2);
}

extern "C" void kernel_launch(void* const* d_in, const int* in_sizes, int n_in,
                              void* d_out, int out_size, void* d_ws, size_t ws_size,
                              hipStream_t stream) {
  (void)in_sizes; (void)n_in; (void)out_size; (void)ws_size;
  const float* x     = (const float*)d_in[0];   // (8,32,224,224,3) f32
  const float* noise = (const float*)d_in[1];   // (4,766) f32
  const float* basis = (const float*)d_in[2];   // (4,3,3) f32
  float* out  = (float*)d_out;
  float* Mbuf = (float*)d_ws;                   // 256*9 floats scratch

  build_mats_v2<<<NFRAMES, 256, 0, stream>>>(noise, basis, Mbuf);
  warp_bilinear_kernel<<<NFRAMES * BLOCKS_PER_FRAME, 256, 0, stream>>>(x, Mbuf, out);
}